// Round 2
// baseline (317.552 us; speedup 1.0000x reference)
//
#include <hip/hip_runtime.h>
#include <stdint.h>

// NBEATS seasonal KAN block, MI355X bf16-MFMA implementation.
// Layer l: Act[b, f*512+i] (f=0: silu, f=1..8: bspline) @ Wt[o, f*512+i].
// Split-K GEMM -> fp32 partials; reduction fused into next expand.
// ws usage ~74 MB.

typedef unsigned short u16;
typedef __attribute__((ext_vector_type(8))) short short8;   // 8 bf16 (4 VGPRs)
typedef __attribute__((ext_vector_type(4))) float f32x4;    // MFMA accum

#define NB 2048      // batch
#define KD 4608      // 9*512 expanded K
#define NTH 128      // theta dim
#define NTT 640      // BACK+FORE

__device__ __forceinline__ u16 f2bf(float f) {
  union { float f; uint32_t u; } c; c.f = f;
  return (u16)((c.u + 0x7FFFu + ((c.u >> 16) & 1u)) >> 16);   // RNE
}

__device__ __forceinline__ void load_lds16(const void* g, void* lds) {
  __builtin_amdgcn_global_load_lds((const __attribute__((address_space(1))) void*)g,
                                   (__attribute__((address_space(3))) void*)lds, 16, 0, 0);
}

// ---------- weight pack: Wt[(l*O+o)][f*512+i] ----------
__global__ void prep_w(const float* __restrict__ coef, const float* __restrict__ sb,
                       const float* __restrict__ ssp, u16* __restrict__ Wt, int O) {
  const int i = blockIdx.x * 64 + threadIdx.x;
  const int o = blockIdx.y * 8 + threadIdx.y;
  const int l = blockIdx.z;
  const size_t io = ((size_t)l * 512 + i) * (size_t)O + o;
  const float sspv = ssp[io];
  const float4 a = *(const float4*)(coef + io * 8);
  const float4 b = *(const float4*)(coef + io * 8 + 4);
  u16* w = Wt + ((size_t)l * O + o) * KD;
  w[i] = f2bf(sb[io]);
  w[1*512 + i] = f2bf(a.x * sspv);
  w[2*512 + i] = f2bf(a.y * sspv);
  w[3*512 + i] = f2bf(a.z * sspv);
  w[4*512 + i] = f2bf(a.w * sspv);
  w[5*512 + i] = f2bf(b.x * sspv);
  w[6*512 + i] = f2bf(b.y * sspv);
  w[7*512 + i] = f2bf(b.z * sspv);
  w[8*512 + i] = f2bf(b.w * sspv);
}

// ---------- bspline (K=3, NUM=5, uniform grid g[j]=0.4j-2.2) ----------
__device__ __forceinline__ void bspline8(float x, float* v8) {
  float g[12];
  #pragma unroll
  for (int j = 0; j < 12; ++j) g[j] = (float)((j - 3) * 0.4 - 1.0);  // matches numpy fp64->fp32
  float v[11];
  #pragma unroll
  for (int j = 0; j < 11; ++j) v[j] = (x >= g[j] && x < g[j+1]) ? 1.0f : 0.0f;
  #pragma unroll
  for (int p = 1; p <= 3; ++p) {
    #pragma unroll
    for (int j = 0; j < 11 - p; ++j) {
      float t1 = (x - g[j]) / (g[j+p] - g[j]);
      float t2 = (g[j+p+1] - x) / (g[j+p+1] - g[j+1]);
      v[j] = t1 * v[j] + t2 * v[j+1];
    }
  }
  #pragma unroll
  for (int j = 0; j < 8; ++j) v8[j] = v[j];
}

// ---------- expand: h (or sum of NSUM split-K partials) -> Act bf16 ----------
template<int NSUM>
__global__ void expand_kernel(const float* __restrict__ src, u16* __restrict__ Act,
                              size_t strideP) {
  const int i = threadIdx.x;            // 0..511
  const int b = blockIdx.x;             // 0..2047
  const size_t idx = (size_t)b * 512 + i;
  float x;
  if (NSUM == 0) {
    x = src[idx];
  } else {
    float s = 0.f;
    #pragma unroll
    for (int t = 0; t < NSUM; ++t) s += src[(size_t)t * strideP + idx];
    x = s;
  }
  const float base = x / (1.0f + expf(-x));   // silu
  float v[8];
  bspline8(x, v);
  u16* row = Act + (size_t)b * KD;
  row[i] = f2bf(base);
  #pragma unroll
  for (int k = 0; k < 8; ++k) row[(1 + k) * 512 + i] = f2bf(v[k]);
}

// ---------- bf16 GEMM, split-K: Cp[z] = A(2048xKD-slice) * Bt(N x KD)^T ----------
// 128x128 tile, BK=64, 4 waves x (4x4) 16x16x32 fragments.
// LDS tiles [128 rows][64 k] bf16 with 16B-chunk XOR swizzle (chunk ^= row&7):
// write side pre-swizzles the *global* source (global_load_lds dest is linear),
// read side applies the same XOR -> conflict-free ds_read_b128.
__global__ __launch_bounds__(256, 2)
void gemm_bf16_splitk(const u16* __restrict__ A, const u16* __restrict__ Bt,
                      float* __restrict__ Cp, int N, int kIter) {
  __shared__ u16 As[128 * 64];
  __shared__ u16 Bs[128 * 64];
  const int tid  = threadIdx.x;
  const int wave = tid >> 6;
  const int lane = tid & 63;
  const int rowBase = blockIdx.x * 128;
  const int colBase = blockIdx.y * 128;
  const int kb0 = blockIdx.z * kIter;

  const int wr = wave >> 1, wc = wave & 1;   // 2x2 wave grid, 64x64 each
  const int lr = lane & 15;
  const int lk8 = lane >> 4;                 // 0..3
  const int sRow   = lane >> 3;              // staging: row within 8-row group
  const int sChunk = (lane & 7) ^ sRow;      // pre-swizzled logical 16B chunk

  f32x4 acc[4][4] = {};

  for (int kb = kb0; kb < kb0 + kIter; ++kb) {
    const int kOff = kb * 64;
    #pragma unroll
    for (int j = 0; j < 4; ++j) {
      const int slot = (wave * 4 + j) * 8;   // starting LDS row (8 rows/instr)
      const u16* gA = A  + (size_t)(rowBase + slot + sRow) * KD + kOff + sChunk * 8;
      load_lds16(gA, (void*)(As + slot * 64));
      const u16* gB = Bt + (size_t)(colBase + slot + sRow) * KD + kOff + sChunk * 8;
      load_lds16(gB, (void*)(Bs + slot * 64));
    }
    __syncthreads();   // compiler drains vmcnt before barrier
    #pragma unroll
    for (int ks = 0; ks < 2; ++ks) {
      short8 af[4], bf[4];
      const int kc = ks * 4 + lk8;           // 16B chunk index along k (0..7)
      #pragma unroll
      for (int m = 0; m < 4; ++m) {
        const int r = wr * 64 + m * 16 + lr;
        af[m] = *(const short8*)(As + r * 64 + ((kc ^ (r & 7)) * 8));
      }
      #pragma unroll
      for (int n = 0; n < 4; ++n) {
        const int r = wc * 64 + n * 16 + lr;
        bf[n] = *(const short8*)(Bs + r * 64 + ((kc ^ (r & 7)) * 8));
      }
      #pragma unroll
      for (int m = 0; m < 4; ++m)
        #pragma unroll
        for (int n = 0; n < 4; ++n)
          acc[m][n] = __builtin_amdgcn_mfma_f32_16x16x32_bf16(af[m], bf[n], acc[m][n], 0, 0, 0);
    }
    __syncthreads();
  }

  float* out = Cp + (size_t)blockIdx.z * (size_t)NB * N;
  #pragma unroll
  for (int m = 0; m < 4; ++m) {
    const int row0 = rowBase + wr * 64 + m * 16 + (lane >> 4) * 4;  // C/D: row=(l>>4)*4+reg
    #pragma unroll
    for (int n = 0; n < 4; ++n) {
      const int col = colBase + wc * 64 + n * 16 + lr;              // C/D: col=l&15
      #pragma unroll
      for (int r = 0; r < 4; ++r)
        out[(size_t)(row0 + r) * N + col] = acc[m][n][r];
    }
  }
}

// ---------- theta reduce (18 split-K partials) ----------
__global__ void reduce_theta(const float* __restrict__ P, float* __restrict__ theta) {
  const size_t idx = (size_t)blockIdx.x * 256 + threadIdx.x;  // < 2048*128
  float s = 0.f;
  #pragma unroll
  for (int t = 0; t < 18; ++t) s += P[(size_t)t * NB * NTH + idx];
  theta[idx] = s;
}

// ---------- seasonal basis S[j][t] = cos/sin(2*pi*(j*t mod 63)/63) ----------
__global__ void sgen(float* __restrict__ S) {
  const int t = blockIdx.x;      // 0..639
  const int j = threadIdx.x;     // 0..127
  const int m = ((j & 63) * t) % 63;
  const float ang = (float)(6.283185307179586 * (double)m / 63.0);
  S[(size_t)j * NTT + t] = (j < 64) ? cosf(ang) : sinf(ang);
}

// ---------- fp32 projection: out = theta(2048x128) @ S(128x640) ----------
__global__ void proj_kernel(const float* __restrict__ theta, const float* __restrict__ S,
                            float* __restrict__ out) {
  __shared__ float Ts[64][129];
  const int tid  = threadIdx.y * 16 + threadIdx.x;
  const int brow = blockIdx.x * 64, bcol = blockIdx.y * 64;
  for (int idx = tid; idx < 64 * 128; idx += 256) {
    const int r = idx >> 7, c = idx & 127;
    Ts[r][c] = theta[(size_t)(brow + r) * NTH + c];
  }
  __syncthreads();
  const int r0 = threadIdx.y * 4, c0 = threadIdx.x * 4;
  float acc[4][4] = {};
  for (int k = 0; k < 128; ++k) {
    const float4 sv = *(const float4*)(S + (size_t)k * NTT + bcol + c0);
    #pragma unroll
    for (int rr = 0; rr < 4; ++rr) {
      const float tv = Ts[r0 + rr][k];
      acc[rr][0] += tv * sv.x; acc[rr][1] += tv * sv.y;
      acc[rr][2] += tv * sv.z; acc[rr][3] += tv * sv.w;
    }
  }
  #pragma unroll
  for (int rr = 0; rr < 4; ++rr) {
    const int b = brow + r0 + rr;
    #pragma unroll
    for (int cc = 0; cc < 4; ++cc) {
      const int t = bcol + c0 + cc;
      if (t < 512) out[(size_t)b * 512 + t] = acc[rr][cc];                      // backcast
      else         out[(size_t)NB * 512 + (size_t)b * 128 + (t - 512)] = acc[rr][cc]; // forecast
    }
  }
}

extern "C" void kernel_launch(void* const* d_in, const int* in_sizes, int n_in,
                              void* d_out, int out_size, void* d_ws, size_t ws_size,
                              hipStream_t stream) {
  (void)in_sizes; (void)n_in; (void)out_size; (void)ws_size;
  const float* x       = (const float*)d_in[0];
  const float* coef_fc = (const float*)d_in[1];
  const float* sb_fc   = (const float*)d_in[2];
  const float* ssp_fc  = (const float*)d_in[3];
  const float* coef_th = (const float*)d_in[4];
  const float* sb_th   = (const float*)d_in[5];
  const float* ssp_th  = (const float*)d_in[6];
  float* out = (float*)d_out;

  // ws layout (bytes): WtFc 18.9M | WtTh 1.18M | Act 18.9M | Part 33.6M | theta 1.05M | S 0.33M
  u16*  WtFc  = (u16*)d_ws;
  u16*  WtTh  = WtFc + (size_t)4 * 512 * KD;
  u16*  Act   = WtTh + (size_t)NTH * KD;
  float* Part = (float*)(Act + (size_t)NB * KD);
  float* theta = Part + (size_t)8 * NB * 512;
  float* S     = theta + (size_t)NB * NTH;

  prep_w<<<dim3(8, 64, 4), dim3(64, 8), 0, stream>>>(coef_fc, sb_fc, ssp_fc, WtFc, 512);
  prep_w<<<dim3(8, 16, 1), dim3(64, 8), 0, stream>>>(coef_th, sb_th, ssp_th, WtTh, 128);
  sgen<<<dim3(NTT), dim3(128), 0, stream>>>(S);

  expand_kernel<0><<<dim3(NB), dim3(512), 0, stream>>>(x, Act, 0);
  for (int l = 0; l < 4; ++l) {
    gemm_bf16_splitk<<<dim3(16, 4, 8), dim3(256), 0, stream>>>(
        Act, WtFc + (size_t)l * 512 * KD, Part, 512, 9);           // 72 kb / 8 splits
    expand_kernel<8><<<dim3(NB), dim3(512), 0, stream>>>(Part, Act, (size_t)NB * 512);
  }
  gemm_bf16_splitk<<<dim3(16, 1, 18), dim3(256), 0, stream>>>(
      Act, WtTh, Part, NTH, 4);                                    // 72 kb / 18 splits
  reduce_theta<<<dim3(NB * NTH / 256), dim3(256), 0, stream>>>(Part, theta);
  proj_kernel<<<dim3(32, 10), dim3(16, 16), 0, stream>>>(theta, S, out);
}

// Round 5
// 245.690 us; speedup vs baseline: 1.2925x; 1.2925x over previous
//
#include <hip/hip_runtime.h>
#include <stdint.h>

// NBEATS seasonal KAN block — multi-kernel (proven skeleton) + dbuf GEMM,
// div-free bspline, LDS-transposed weight pack, fused theta-reduce in proj.
// 12 dispatches. ws ~56 MB.

typedef unsigned short u16;
typedef __attribute__((ext_vector_type(8))) short short8;   // 8 bf16
typedef __attribute__((ext_vector_type(4))) float f32x4;    // MFMA accum

#define NB 2048      // batch
#define KD 4608      // 9*512 expanded K
#define NTH 128      // theta dim
#define NTT 640      // BACK+FORE

__device__ __forceinline__ u16 f2bf(float f) {
  union { float f; uint32_t u; } c; c.f = f;
  return (u16)((c.u + 0x7FFFu + ((c.u >> 16) & 1u)) >> 16);   // RNE
}

__device__ __forceinline__ void load_lds16(const void* g, void* lds) {
  __builtin_amdgcn_global_load_lds((const __attribute__((address_space(1))) void*)g,
                                   (__attribute__((address_space(3))) void*)lds, 16, 0, 0);
}

// ---------- bspline (K=3, NUM=5, uniform grid g[j]=0.4j-2.2), div-free ----------
__device__ __forceinline__ void bspline8(float x, float* v8) {
  float g[12];
  #pragma unroll
  for (int j = 0; j < 12; ++j) g[j] = (float)((j - 3) * 0.4 - 1.0);
  float w[11];
  #pragma unroll
  for (int j = 0; j < 11; ++j) w[j] = (x >= g[j] && x < g[j+1]) ? 1.0f : 0.0f;
  #pragma unroll
  for (int p = 1; p <= 3; ++p) {
    #pragma unroll
    for (int j = 0; j < 11 - p; ++j) {
      const float i1 = 1.0f / (g[j+p] - g[j]);      // compile-time constants
      const float i2 = 1.0f / (g[j+p+1] - g[j+1]);
      w[j] = (x - g[j]) * i1 * w[j] + (g[j+p+1] - x) * i2 * w[j+1];
    }
  }
  #pragma unroll
  for (int j = 0; j < 8; ++j) v8[j] = w[j];
}

__device__ __forceinline__ void expand_one(float xv, u16* __restrict__ row, int i) {
  const float base = xv / (1.0f + __expf(-xv));   // silu
  float v[8];
  bspline8(xv, v);
  row[i] = f2bf(base);
  #pragma unroll
  for (int k = 0; k < 8; ++k) row[(1 + k) * 512 + i] = f2bf(v[k]);
}

// ---------- setup: weight pack (LDS transpose) + seasonal basis ----------
// blocks 0..255: fc tiles (4l x 8i x 8o of 64x64)
// blocks 256..271: th tiles (8i x 2o)
// blocks 272..291: S[j][t] = cos/sin(2pi*(j*t mod 63)/63)
__global__ __launch_bounds__(256)
void setup_kernel(const float* __restrict__ coef_fc, const float* __restrict__ sb_fc,
                  const float* __restrict__ ssp_fc,  const float* __restrict__ coef_th,
                  const float* __restrict__ sb_th,   const float* __restrict__ ssp_th,
                  u16* __restrict__ WtFc, u16* __restrict__ WtTh, float* __restrict__ S) {
  const int blk = blockIdx.x, tid = threadIdx.x;
  __shared__ u16 T[9 * 64 * 66];                 // 76 KB, pad 66 -> stride 33 dwords
  if (blk < 272) {
    const float *coef, *sb, *ssp; u16* Wt; int O, l, i0, o0;
    if (blk < 256) {
      coef = coef_fc; sb = sb_fc; ssp = ssp_fc; Wt = WtFc; O = 512;
      l = blk >> 6; i0 = ((blk >> 3) & 7) * 64; o0 = (blk & 7) * 64;
    } else {
      coef = coef_th; sb = sb_th; ssp = ssp_th; Wt = WtTh; O = 128;
      const int t = blk - 256;
      l = 0; i0 = (t >> 1) * 64; o0 = (t & 1) * 64;
    }
    #pragma unroll 4
    for (int pass = 0; pass < 16; ++pass) {      // read: lanes along o (coalesced)
      const int o_loc = tid & 63;
      const int i_loc = pass * 4 + (tid >> 6);
      const size_t io = ((size_t)l * 512 + i0 + i_loc) * (size_t)O + o0 + o_loc;
      const float sspv = ssp[io];
      const float4 a = *(const float4*)(coef + io * 8);
      const float4 b = *(const float4*)(coef + io * 8 + 4);
      u16* t0 = T + i_loc * 66 + o_loc;
      t0[0 * 64 * 66] = f2bf(sb[io]);
      t0[1 * 64 * 66] = f2bf(a.x * sspv);
      t0[2 * 64 * 66] = f2bf(a.y * sspv);
      t0[3 * 64 * 66] = f2bf(a.z * sspv);
      t0[4 * 64 * 66] = f2bf(a.w * sspv);
      t0[5 * 64 * 66] = f2bf(b.x * sspv);
      t0[6 * 64 * 66] = f2bf(b.y * sspv);
      t0[7 * 64 * 66] = f2bf(b.z * sspv);
      t0[8 * 64 * 66] = f2bf(b.w * sspv);
    }
    __syncthreads();
    #pragma unroll
    for (int f = 0; f < 9; ++f)                  // write: lanes along i (coalesced)
      #pragma unroll 4
      for (int pass = 0; pass < 16; ++pass) {
        const int i_loc = tid & 63;
        const int o_loc = pass * 4 + (tid >> 6);
        Wt[((size_t)l * O + o0 + o_loc) * KD + f * 512 + i0 + i_loc] =
            T[(f * 64 + i_loc) * 66 + o_loc];
      }
  } else {
    const int base = (blk - 272) * 4096;
    #pragma unroll 4
    for (int q = 0; q < 16; ++q) {
      const int id = base + q * 256 + tid;       // < 81920
      const int j = id & 127, t = id >> 7;
      const int m = ((j & 63) * t) % 63;
      const float ang = (float)(6.283185307179586 * (double)m / 63.0);
      S[(size_t)j * NTT + t] = (j < 64) ? cosf(ang) : sinf(ang);
    }
  }
}

// ---------- expand: h (or sum of NSUM split-K partials) -> Act bf16 ----------
template<int NSUM>
__global__ __launch_bounds__(256)
void expand_kernel(const float* __restrict__ src, u16* __restrict__ Act) {
  #pragma unroll
  for (int q = 0; q < 4; ++q) {
    const int id = blockIdx.x * 1024 + q * 256 + threadIdx.x;   // < 2048*512
    const int b = id >> 9, i = id & 511;
    float xv;
    if (NSUM == 0) {
      xv = src[id];
    } else {
      float s = 0.f;
      #pragma unroll
      for (int t = 0; t < NSUM; ++t) s += src[(size_t)t * NB * 512 + id];
      xv = s;
    }
    expand_one(xv, Act + (size_t)b * KD, i);
  }
}

// ---------- bf16 GEMM, split-K, double-buffered (T3 2-phase) ----------
// 128x128 tile, BK=64, 4 waves x (4x4) 16x16x32 frags. XOR-chunk LDS swizzle.
__global__ __launch_bounds__(256, 2)
void gemm_dbuf(const u16* __restrict__ A, const u16* __restrict__ Bt,
               float* __restrict__ Cp, int N, int kIter) {
  __shared__ __align__(16) u16 sm[4 * 8192];     // As0|Bs0|As1|Bs1
  u16* As0 = sm;          u16* Bs0 = sm + 8192;
  u16* As1 = sm + 16384;  u16* Bs1 = sm + 24576;
  const int tid  = threadIdx.x;
  const int wave = tid >> 6, lane = tid & 63;
  const int rowBase = blockIdx.x * 128, colBase = blockIdx.y * 128;
  const int kb0 = blockIdx.z * kIter;
  const int wr = wave >> 1, wc = wave & 1;
  const int lr = lane & 15, lk8 = lane >> 4;
  const int sRow   = lane >> 3;
  const int sChunk = (lane & 7) ^ sRow;          // pre-swizzled global 16B chunk

  f32x4 acc[4][4] = {};
  u16 *Asc = As0, *Bsc = Bs0, *Asn = As1, *Bsn = Bs1;

  // prologue: stage tile 0
  #pragma unroll
  for (int j = 0; j < 4; ++j) {
    const int slot = (wave * 4 + j) * 8;
    load_lds16(A  + (size_t)(rowBase + slot + sRow) * KD + kb0 * 64 + sChunk * 8, Asc + slot * 64);
    load_lds16(Bt + (size_t)(colBase + slot + sRow) * KD + kb0 * 64 + sChunk * 8, Bsc + slot * 64);
  }
  asm volatile("s_waitcnt vmcnt(0)" ::: "memory");
  __builtin_amdgcn_s_barrier();

  for (int t = 0; t < kIter; ++t) {
    if (t + 1 < kIter) {                         // stage next tile (flies under MFMA)
      const int kOff = (kb0 + t + 1) * 64;
      #pragma unroll
      for (int j = 0; j < 4; ++j) {
        const int slot = (wave * 4 + j) * 8;
        load_lds16(A  + (size_t)(rowBase + slot + sRow) * KD + kOff + sChunk * 8, Asn + slot * 64);
        load_lds16(Bt + (size_t)(colBase + slot + sRow) * KD + kOff + sChunk * 8, Bsn + slot * 64);
      }
    }
    #pragma unroll
    for (int ks = 0; ks < 2; ++ks) {
      short8 af[4], bf[4];
      const int kc = ks * 4 + lk8;
      #pragma unroll
      for (int m = 0; m < 4; ++m) {
        const int r = wr * 64 + m * 16 + lr;
        af[m] = *(const short8*)(Asc + r * 64 + ((kc ^ (r & 7)) * 8));
      }
      #pragma unroll
      for (int n = 0; n < 4; ++n) {
        const int r = wc * 64 + n * 16 + lr;
        bf[n] = *(const short8*)(Bsc + r * 64 + ((kc ^ (r & 7)) * 8));
      }
      #pragma unroll
      for (int m = 0; m < 4; ++m)
        #pragma unroll
        for (int n = 0; n < 4; ++n)
          acc[m][n] = __builtin_amdgcn_mfma_f32_16x16x32_bf16(af[m], bf[n], acc[m][n], 0, 0, 0);
    }
    asm volatile("s_waitcnt vmcnt(0)" ::: "memory");
    __builtin_amdgcn_s_barrier();
    u16* tp;
    tp = Asc; Asc = Asn; Asn = tp;
    tp = Bsc; Bsc = Bsn; Bsn = tp;
  }

  float* out = Cp + (size_t)blockIdx.z * (size_t)NB * N;
  #pragma unroll
  for (int m = 0; m < 4; ++m) {
    const int row0 = rowBase + wr * 64 + m * 16 + (lane >> 4) * 4;   // row=(l>>4)*4+reg
    #pragma unroll
    for (int n = 0; n < 4; ++n) {
      const int col = colBase + wc * 64 + n * 16 + lr;               // col=l&15
      #pragma unroll
      for (int r = 0; r < 4; ++r)
        out[(size_t)(row0 + r) * N + col] = acc[m][n][r];
    }
  }
}

// ---------- proj (+8-partial theta reduce): out = theta(2048x128) @ S(128x640) ----------
__global__ __launch_bounds__(256)
void proj_kernel(const float* __restrict__ Part, const float* __restrict__ S,
                 float* __restrict__ out) {
  __shared__ float Ts[64][129];
  const int tid = threadIdx.x;
  const int brow = blockIdx.x * 64, bcol = blockIdx.y * 64;
  for (int idx = tid; idx < 64 * 128; idx += 256) {
    const int r = idx >> 7, c = idx & 127;
    float s = 0.f;
    #pragma unroll
    for (int t = 0; t < 8; ++t)
      s += Part[(size_t)t * NB * NTH + (size_t)(brow + r) * NTH + c];
    Ts[r][c] = s;
  }
  __syncthreads();
  const int tx = tid & 15, ty = tid >> 4;
  const int r0 = ty * 4, c0 = tx * 4;
  float acc[4][4] = {};
  for (int k = 0; k < 128; ++k) {
    const float4 sv = *(const float4*)(S + (size_t)k * NTT + bcol + c0);
    #pragma unroll
    for (int rr = 0; rr < 4; ++rr) {
      const float tv = Ts[r0 + rr][k];
      acc[rr][0] += tv * sv.x; acc[rr][1] += tv * sv.y;
      acc[rr][2] += tv * sv.z; acc[rr][3] += tv * sv.w;
    }
  }
  #pragma unroll
  for (int rr = 0; rr < 4; ++rr) {
    const int b = brow + r0 + rr;
    #pragma unroll
    for (int cc = 0; cc < 4; ++cc) {
      const int t = bcol + c0 + cc;
      if (t < 512) out[(size_t)b * 512 + t] = acc[rr][cc];                            // backcast
      else         out[(size_t)NB * 512 + (size_t)b * NTH + (t - 512)] = acc[rr][cc]; // forecast
    }
  }
}

extern "C" void kernel_launch(void* const* d_in, const int* in_sizes, int n_in,
                              void* d_out, int out_size, void* d_ws, size_t ws_size,
                              hipStream_t stream) {
  (void)in_sizes; (void)n_in; (void)out_size; (void)ws_size;
  const float* x       = (const float*)d_in[0];
  const float* coef_fc = (const float*)d_in[1];
  const float* sb_fc   = (const float*)d_in[2];
  const float* ssp_fc  = (const float*)d_in[3];
  const float* coef_th = (const float*)d_in[4];
  const float* sb_th   = (const float*)d_in[5];
  const float* ssp_th  = (const float*)d_in[6];
  float* out = (float*)d_out;

  // ws layout: WtFc 18.9M | WtTh 1.18M | Act 18.9M | Part 16.8M | S 0.33M
  u16*  WtFc = (u16*)d_ws;
  u16*  WtTh = WtFc + (size_t)4 * 512 * KD;
  u16*  Act  = WtTh + (size_t)NTH * KD;
  float* Part = (float*)(Act + (size_t)NB * KD);
  float* S    = Part + (size_t)4 * NB * 512;

  setup_kernel<<<dim3(292), dim3(256), 0, stream>>>(coef_fc, sb_fc, ssp_fc,
                                                    coef_th, sb_th, ssp_th,
                                                    WtFc, WtTh, S);
  expand_kernel<0><<<dim3(1024), dim3(256), 0, stream>>>(x, Act);
  for (int l = 0; l < 4; ++l) {
    gemm_dbuf<<<dim3(16, 4, 4), dim3(256), 0, stream>>>(
        Act, WtFc + (size_t)l * 512 * KD, Part, 512, 18);   // 72 kb / 4 splits
    expand_kernel<4><<<dim3(1024), dim3(256), 0, stream>>>(Part, Act);
  }
  gemm_dbuf<<<dim3(16, 1, 8), dim3(256), 0, stream>>>(
      Act, WtTh, Part, NTH, 9);                             // 72 kb / 8 splits
  proj_kernel<<<dim3(32, 10), dim3(256), 0, stream>>>(Part, S, out);
}

// Round 6
// 241.485 us; speedup vs baseline: 1.3150x; 1.0174x over previous
//
#include <hip/hip_runtime.h>
#include <stdint.h>

// NBEATS seasonal KAN block — multi-kernel, dbuf GEMM with XCD-locality swizzle.
// fc GEMM: 1-D grid 256, id -> (bx,by,bz) s.t. A-panel-sharing quad on one XCD,
// W-panel-sharing group on 2 XCDs. 12 dispatches. ws ~56 MB.

typedef unsigned short u16;
typedef __attribute__((ext_vector_type(8))) short short8;   // 8 bf16
typedef __attribute__((ext_vector_type(4))) float f32x4;    // MFMA accum

#define NB 2048      // batch
#define KD 4608      // 9*512 expanded K
#define NTH 128      // theta dim
#define NTT 640      // BACK+FORE

__device__ __forceinline__ u16 f2bf(float f) {
  union { float f; uint32_t u; } c; c.f = f;
  return (u16)((c.u + 0x7FFFu + ((c.u >> 16) & 1u)) >> 16);   // RNE
}

__device__ __forceinline__ void load_lds16(const void* g, void* lds) {
  __builtin_amdgcn_global_load_lds((const __attribute__((address_space(1))) void*)g,
                                   (__attribute__((address_space(3))) void*)lds, 16, 0, 0);
}

// ---------- bspline (K=3, NUM=5, uniform grid g[j]=0.4j-2.2), div-free ----------
__device__ __forceinline__ void bspline8(float x, float* v8) {
  float g[12];
  #pragma unroll
  for (int j = 0; j < 12; ++j) g[j] = (float)((j - 3) * 0.4 - 1.0);
  float w[11];
  #pragma unroll
  for (int j = 0; j < 11; ++j) w[j] = (x >= g[j] && x < g[j+1]) ? 1.0f : 0.0f;
  #pragma unroll
  for (int p = 1; p <= 3; ++p) {
    #pragma unroll
    for (int j = 0; j < 11 - p; ++j) {
      const float i1 = 1.0f / (g[j+p] - g[j]);      // compile-time constants
      const float i2 = 1.0f / (g[j+p+1] - g[j+1]);
      w[j] = (x - g[j]) * i1 * w[j] + (g[j+p+1] - x) * i2 * w[j+1];
    }
  }
  #pragma unroll
  for (int j = 0; j < 8; ++j) v8[j] = w[j];
}

__device__ __forceinline__ void expand_one(float xv, u16* __restrict__ row, int i) {
  const float base = xv / (1.0f + __expf(-xv));   // silu
  float v[8];
  bspline8(xv, v);
  row[i] = f2bf(base);
  #pragma unroll
  for (int k = 0; k < 8; ++k) row[(1 + k) * 512 + i] = f2bf(v[k]);
}

// ---------- setup: weight pack (LDS transpose) + seasonal basis ----------
__global__ __launch_bounds__(256)
void setup_kernel(const float* __restrict__ coef_fc, const float* __restrict__ sb_fc,
                  const float* __restrict__ ssp_fc,  const float* __restrict__ coef_th,
                  const float* __restrict__ sb_th,   const float* __restrict__ ssp_th,
                  u16* __restrict__ WtFc, u16* __restrict__ WtTh, float* __restrict__ S) {
  const int blk = blockIdx.x, tid = threadIdx.x;
  __shared__ u16 T[9 * 64 * 66];                 // 76 KB, pad 66 -> stride 33 dwords
  if (blk < 272) {
    const float *coef, *sb, *ssp; u16* Wt; int O, l, i0, o0;
    if (blk < 256) {
      coef = coef_fc; sb = sb_fc; ssp = ssp_fc; Wt = WtFc; O = 512;
      l = blk >> 6; i0 = ((blk >> 3) & 7) * 64; o0 = (blk & 7) * 64;
    } else {
      coef = coef_th; sb = sb_th; ssp = ssp_th; Wt = WtTh; O = 128;
      const int t = blk - 256;
      l = 0; i0 = (t >> 1) * 64; o0 = (t & 1) * 64;
    }
    #pragma unroll 4
    for (int pass = 0; pass < 16; ++pass) {      // read: lanes along o (coalesced)
      const int o_loc = tid & 63;
      const int i_loc = pass * 4 + (tid >> 6);
      const size_t io = ((size_t)l * 512 + i0 + i_loc) * (size_t)O + o0 + o_loc;
      const float sspv = ssp[io];
      const float4 a = *(const float4*)(coef + io * 8);
      const float4 b = *(const float4*)(coef + io * 8 + 4);
      u16* t0 = T + i_loc * 66 + o_loc;
      t0[0 * 64 * 66] = f2bf(sb[io]);
      t0[1 * 64 * 66] = f2bf(a.x * sspv);
      t0[2 * 64 * 66] = f2bf(a.y * sspv);
      t0[3 * 64 * 66] = f2bf(a.z * sspv);
      t0[4 * 64 * 66] = f2bf(a.w * sspv);
      t0[5 * 64 * 66] = f2bf(b.x * sspv);
      t0[6 * 64 * 66] = f2bf(b.y * sspv);
      t0[7 * 64 * 66] = f2bf(b.z * sspv);
      t0[8 * 64 * 66] = f2bf(b.w * sspv);
    }
    __syncthreads();
    #pragma unroll
    for (int f = 0; f < 9; ++f)                  // write: lanes along i (coalesced)
      #pragma unroll 4
      for (int pass = 0; pass < 16; ++pass) {
        const int i_loc = tid & 63;
        const int o_loc = pass * 4 + (tid >> 6);
        Wt[((size_t)l * O + o0 + o_loc) * KD + f * 512 + i0 + i_loc] =
            T[(f * 64 + i_loc) * 66 + o_loc];
      }
  } else {
    const int base = (blk - 272) * 4096;
    #pragma unroll 4
    for (int q = 0; q < 16; ++q) {
      const int id = base + q * 256 + tid;       // < 81920
      const int j = id & 127, t = id >> 7;
      const int m = ((j & 63) * t) % 63;
      const float ang = (float)(6.283185307179586 * (double)m / 63.0);
      S[(size_t)j * NTT + t] = (j < 64) ? cosf(ang) : sinf(ang);
    }
  }
}

// ---------- expand: h (or sum of NSUM split-K partials) -> Act bf16 ----------
template<int NSUM>
__global__ __launch_bounds__(256)
void expand_kernel(const float* __restrict__ src, u16* __restrict__ Act) {
  #pragma unroll
  for (int q = 0; q < 4; ++q) {
    const int id = blockIdx.x * 1024 + q * 256 + threadIdx.x;   // < 2048*512
    const int b = id >> 9, i = id & 511;
    float xv;
    if (NSUM == 0) {
      xv = src[id];
    } else {
      float s = 0.f;
      #pragma unroll
      for (int t = 0; t < NSUM; ++t) s += src[(size_t)t * NB * 512 + id];
      xv = s;
    }
    expand_one(xv, Act + (size_t)b * KD, i);
  }
}

// ---------- GEMM body (128x128 tile, BK=64, dbuf, XOR-chunk swizzle) ----------
template<int N, int KITER>
__device__ __forceinline__ void gemm_body(const u16* __restrict__ A, const u16* __restrict__ Bt,
                                          float* __restrict__ Cp, int bx, int by, int bz,
                                          u16* sm) {
  u16* As0 = sm;          u16* Bs0 = sm + 8192;
  u16* As1 = sm + 16384;  u16* Bs1 = sm + 24576;
  const int tid  = threadIdx.x;
  const int wave = tid >> 6, lane = tid & 63;
  const int rowBase = bx * 128, colBase = by * 128;
  const int kb0 = bz * KITER;
  const int wr = wave >> 1, wc = wave & 1;
  const int lr = lane & 15, lk8 = lane >> 4;
  const int sRow   = lane >> 3;
  const int sChunk = (lane & 7) ^ sRow;          // pre-swizzled global 16B chunk

  f32x4 acc[4][4] = {};
  u16 *Asc = As0, *Bsc = Bs0, *Asn = As1, *Bsn = Bs1;

  #pragma unroll
  for (int j = 0; j < 4; ++j) {
    const int slot = (wave * 4 + j) * 8;
    load_lds16(A  + (size_t)(rowBase + slot + sRow) * KD + kb0 * 64 + sChunk * 8, Asc + slot * 64);
    load_lds16(Bt + (size_t)(colBase + slot + sRow) * KD + kb0 * 64 + sChunk * 8, Bsc + slot * 64);
  }
  asm volatile("s_waitcnt vmcnt(0)" ::: "memory");
  __builtin_amdgcn_s_barrier();

  for (int t = 0; t < KITER; ++t) {
    if (t + 1 < KITER) {                         // stage next tile (flies under MFMA)
      const int kOff = (kb0 + t + 1) * 64;
      #pragma unroll
      for (int j = 0; j < 4; ++j) {
        const int slot = (wave * 4 + j) * 8;
        load_lds16(A  + (size_t)(rowBase + slot + sRow) * KD + kOff + sChunk * 8, Asn + slot * 64);
        load_lds16(Bt + (size_t)(colBase + slot + sRow) * KD + kOff + sChunk * 8, Bsn + slot * 64);
      }
    }
    #pragma unroll
    for (int ks = 0; ks < 2; ++ks) {
      short8 af[4], bf[4];
      const int kc = ks * 4 + lk8;
      #pragma unroll
      for (int m = 0; m < 4; ++m) {
        const int r = wr * 64 + m * 16 + lr;
        af[m] = *(const short8*)(Asc + r * 64 + ((kc ^ (r & 7)) * 8));
      }
      #pragma unroll
      for (int n = 0; n < 4; ++n) {
        const int r = wc * 64 + n * 16 + lr;
        bf[n] = *(const short8*)(Bsc + r * 64 + ((kc ^ (r & 7)) * 8));
      }
      #pragma unroll
      for (int m = 0; m < 4; ++m)
        #pragma unroll
        for (int n = 0; n < 4; ++n)
          acc[m][n] = __builtin_amdgcn_mfma_f32_16x16x32_bf16(af[m], bf[n], acc[m][n], 0, 0, 0);
    }
    asm volatile("s_waitcnt vmcnt(0)" ::: "memory");
    __builtin_amdgcn_s_barrier();
    u16* tp;
    tp = Asc; Asc = Asn; Asn = tp;
    tp = Bsc; Bsc = Bsn; Bsn = tp;
  }

  float* out = Cp + (size_t)bz * (size_t)NB * N;
  #pragma unroll
  for (int m = 0; m < 4; ++m) {
    const int row0 = rowBase + wr * 64 + m * 16 + (lane >> 4) * 4;   // row=(l>>4)*4+reg
    #pragma unroll
    for (int n = 0; n < 4; ++n) {
      const int col = colBase + wc * 64 + n * 16 + lr;               // col=l&15
      #pragma unroll
      for (int r = 0; r < 4; ++r)
        out[(size_t)(row0 + r) * N + col] = acc[m][n][r];
    }
  }
}

// fc GEMM: 1-D grid 256, XCD-locality swizzle.
// xcd = id&7 = 2*bz + (bx&1); u = id>>3: bx = ((u&7)<<1)|(xcd&1), by = u>>3.
// -> A-panel quad (by=0..3) on ONE XCD; W-panel group (16 bx) on 2 XCDs.
__global__ __launch_bounds__(256, 2)
void gemm_fc(const u16* __restrict__ A, const u16* __restrict__ Bt, float* __restrict__ Cp) {
  __shared__ __align__(16) u16 sm[4 * 8192];     // 64 KiB
  const int id  = blockIdx.x;
  const int xcd = id & 7;
  const int bz  = xcd >> 1;
  const int u   = id >> 3;
  const int bx  = ((u & 7) << 1) | (xcd & 1);
  const int by  = u >> 3;
  gemm_body<512, 18>(A, Bt, Cp, bx, by, bz, sm);
}

// theta GEMM: grid (16,1,8), kIter=9
__global__ __launch_bounds__(256, 2)
void gemm_th(const u16* __restrict__ A, const u16* __restrict__ Bt, float* __restrict__ Cp) {
  __shared__ __align__(16) u16 sm[4 * 8192];
  gemm_body<NTH, 9>(A, Bt, Cp, blockIdx.x, 0, blockIdx.z, sm);
}

// ---------- proj (+8-partial theta reduce): out = theta(2048x128) @ S(128x640) ----------
__global__ __launch_bounds__(256)
void proj_kernel(const float* __restrict__ Part, const float* __restrict__ S,
                 float* __restrict__ out) {
  __shared__ float Ts[64][129];
  const int tid = threadIdx.x;
  const int brow = blockIdx.x * 64, bcol = blockIdx.y * 64;
  for (int idx = tid; idx < 64 * 128; idx += 256) {
    const int r = idx >> 7, c = idx & 127;
    float s = 0.f;
    #pragma unroll
    for (int t = 0; t < 8; ++t)
      s += Part[(size_t)t * NB * NTH + (size_t)(brow + r) * NTH + c];
    Ts[r][c] = s;
  }
  __syncthreads();
  const int tx = tid & 15, ty = tid >> 4;
  const int r0 = ty * 4, c0 = tx * 4;
  float acc[4][4] = {};
  for (int k = 0; k < 128; ++k) {
    const float4 sv = *(const float4*)(S + (size_t)k * NTT + bcol + c0);
    #pragma unroll
    for (int rr = 0; rr < 4; ++rr) {
      const float tv = Ts[r0 + rr][k];
      acc[rr][0] += tv * sv.x; acc[rr][1] += tv * sv.y;
      acc[rr][2] += tv * sv.z; acc[rr][3] += tv * sv.w;
    }
  }
  #pragma unroll
  for (int rr = 0; rr < 4; ++rr) {
    const int b = brow + r0 + rr;
    #pragma unroll
    for (int cc = 0; cc < 4; ++cc) {
      const int t = bcol + c0 + cc;
      if (t < 512) out[(size_t)b * 512 + t] = acc[rr][cc];                            // backcast
      else         out[(size_t)NB * 512 + (size_t)b * NTH + (t - 512)] = acc[rr][cc]; // forecast
    }
  }
}

extern "C" void kernel_launch(void* const* d_in, const int* in_sizes, int n_in,
                              void* d_out, int out_size, void* d_ws, size_t ws_size,
                              hipStream_t stream) {
  (void)in_sizes; (void)n_in; (void)out_size; (void)ws_size;
  const float* x       = (const float*)d_in[0];
  const float* coef_fc = (const float*)d_in[1];
  const float* sb_fc   = (const float*)d_in[2];
  const float* ssp_fc  = (const float*)d_in[3];
  const float* coef_th = (const float*)d_in[4];
  const float* sb_th   = (const float*)d_in[5];
  const float* ssp_th  = (const float*)d_in[6];
  float* out = (float*)d_out;

  // ws layout: WtFc 18.9M | WtTh 1.18M | Act 18.9M | Part 16.8M | S 0.33M
  u16*  WtFc = (u16*)d_ws;
  u16*  WtTh = WtFc + (size_t)4 * 512 * KD;
  u16*  Act  = WtTh + (size_t)NTH * KD;
  float* Part = (float*)(Act + (size_t)NB * KD);
  float* S    = Part + (size_t)4 * NB * 512;

  setup_kernel<<<dim3(292), dim3(256), 0, stream>>>(coef_fc, sb_fc, ssp_fc,
                                                    coef_th, sb_th, ssp_th,
                                                    WtFc, WtTh, S);
  expand_kernel<0><<<dim3(1024), dim3(256), 0, stream>>>(x, Act);
  for (int l = 0; l < 4; ++l) {
    gemm_fc<<<dim3(256), dim3(256), 0, stream>>>(Act, WtFc + (size_t)l * 512 * KD, Part);
    expand_kernel<4><<<dim3(1024), dim3(256), 0, stream>>>(Part, Act);
  }
  gemm_th<<<dim3(16, 1, 8), dim3(256), 0, stream>>>(Act, WtTh, Part);
  proj_kernel<<<dim3(32, 10), dim3(256), 0, stream>>>(Part, S, out);
}

// Round 7
// 240.088 us; speedup vs baseline: 1.3227x; 1.0058x over previous
//
#include <hip/hip_runtime.h>
#include <stdint.h>

// NBEATS seasonal KAN block — multi-kernel; GEMMs use 3-deep counted-vmcnt
// pipeline (T3+T4); vectorized expand; setup+expand0 merged. 11 dispatches.

typedef unsigned short u16;
typedef __attribute__((ext_vector_type(8))) short short8;   // 8 bf16
typedef __attribute__((ext_vector_type(4))) float f32x4;    // MFMA accum

#define NB 2048      // batch
#define KD 4608      // 9*512 expanded K
#define NTH 128      // theta dim
#define NTT 640      // BACK+FORE

__device__ __forceinline__ u16 f2bf(float f) {
  union { float f; uint32_t u; } c; c.f = f;
  return (u16)((c.u + 0x7FFFu + ((c.u >> 16) & 1u)) >> 16);   // RNE
}

__device__ __forceinline__ void load_lds16(const void* g, void* lds) {
  __builtin_amdgcn_global_load_lds((const __attribute__((address_space(1))) void*)g,
                                   (__attribute__((address_space(3))) void*)lds, 16, 0, 0);
}

// ---------- bspline (K=3, NUM=5, uniform grid g[j]=0.4j-2.2), div-free ----------
__device__ __forceinline__ void bspline8(float x, float* v8) {
  float g[12];
  #pragma unroll
  for (int j = 0; j < 12; ++j) g[j] = (float)((j - 3) * 0.4 - 1.0);
  float w[11];
  #pragma unroll
  for (int j = 0; j < 11; ++j) w[j] = (x >= g[j] && x < g[j+1]) ? 1.0f : 0.0f;
  #pragma unroll
  for (int p = 1; p <= 3; ++p) {
    #pragma unroll
    for (int j = 0; j < 11 - p; ++j) {
      const float i1 = 1.0f / (g[j+p] - g[j]);      // compile-time constants
      const float i2 = 1.0f / (g[j+p+1] - g[j+1]);
      w[j] = (x - g[j]) * i1 * w[j] + (g[j+p+1] - x) * i2 * w[j+1];
    }
  }
  #pragma unroll
  for (int j = 0; j < 8; ++j) v8[j] = w[j];
}

// expand a quad of 4 consecutive inputs -> 9 short4 stores
__device__ __forceinline__ void expand_quad(const float* xv, u16* __restrict__ row, int i0) {
  float base[4], v[4][8];
  #pragma unroll
  for (int e = 0; e < 4; ++e) {
    base[e] = xv[e] / (1.0f + __expf(-xv[e]));   // silu
    bspline8(xv[e], v[e]);
  }
  short4 s;
  s.x = (short)f2bf(base[0]); s.y = (short)f2bf(base[1]);
  s.z = (short)f2bf(base[2]); s.w = (short)f2bf(base[3]);
  *(short4*)(row + i0) = s;
  #pragma unroll
  for (int f = 0; f < 8; ++f) {
    s.x = (short)f2bf(v[0][f]); s.y = (short)f2bf(v[1][f]);
    s.z = (short)f2bf(v[2][f]); s.w = (short)f2bf(v[3][f]);
    *(short4*)(row + (1 + f) * 512 + i0) = s;
  }
}

// ---------- setup: weight pack (LDS transpose) + seasonal basis + expand0 ----------
// blocks 0..255: fc tiles | 256..271: th tiles | 272..291: S | 292..547: expand0
__global__ __launch_bounds__(256)
void setup_kernel(const float* __restrict__ coef_fc, const float* __restrict__ sb_fc,
                  const float* __restrict__ ssp_fc,  const float* __restrict__ coef_th,
                  const float* __restrict__ sb_th,   const float* __restrict__ ssp_th,
                  const float* __restrict__ x,
                  u16* __restrict__ WtFc, u16* __restrict__ WtTh,
                  float* __restrict__ S,  u16* __restrict__ Act) {
  const int blk = blockIdx.x, tid = threadIdx.x;
  __shared__ u16 T[9 * 64 * 66];                 // 76 KB, pad 66 -> stride 33 dwords
  if (blk < 272) {
    const float *coef, *sb, *ssp; u16* Wt; int O, l, i0, o0;
    if (blk < 256) {
      coef = coef_fc; sb = sb_fc; ssp = ssp_fc; Wt = WtFc; O = 512;
      l = blk >> 6; i0 = ((blk >> 3) & 7) * 64; o0 = (blk & 7) * 64;
    } else {
      coef = coef_th; sb = sb_th; ssp = ssp_th; Wt = WtTh; O = 128;
      const int t = blk - 256;
      l = 0; i0 = (t >> 1) * 64; o0 = (t & 1) * 64;
    }
    #pragma unroll 4
    for (int pass = 0; pass < 16; ++pass) {      // read: lanes along o (coalesced)
      const int o_loc = tid & 63;
      const int i_loc = pass * 4 + (tid >> 6);
      const size_t io = ((size_t)l * 512 + i0 + i_loc) * (size_t)O + o0 + o_loc;
      const float sspv = ssp[io];
      const float4 a = *(const float4*)(coef + io * 8);
      const float4 b = *(const float4*)(coef + io * 8 + 4);
      u16* t0 = T + i_loc * 66 + o_loc;
      t0[0 * 64 * 66] = f2bf(sb[io]);
      t0[1 * 64 * 66] = f2bf(a.x * sspv);
      t0[2 * 64 * 66] = f2bf(a.y * sspv);
      t0[3 * 64 * 66] = f2bf(a.z * sspv);
      t0[4 * 64 * 66] = f2bf(a.w * sspv);
      t0[5 * 64 * 66] = f2bf(b.x * sspv);
      t0[6 * 64 * 66] = f2bf(b.y * sspv);
      t0[7 * 64 * 66] = f2bf(b.z * sspv);
      t0[8 * 64 * 66] = f2bf(b.w * sspv);
    }
    __syncthreads();
    #pragma unroll
    for (int f = 0; f < 9; ++f)                  // write: lanes along i (coalesced)
      #pragma unroll 4
      for (int pass = 0; pass < 16; ++pass) {
        const int i_loc = tid & 63;
        const int o_loc = pass * 4 + (tid >> 6);
        Wt[((size_t)l * O + o0 + o_loc) * KD + f * 512 + i0 + i_loc] =
            T[(f * 64 + i_loc) * 66 + o_loc];
      }
  } else if (blk < 292) {
    const int base = (blk - 272) * 4096;
    #pragma unroll 4
    for (int q = 0; q < 16; ++q) {
      const int id = base + q * 256 + tid;       // < 81920 = 128*640
      const int j = id & 127, t = id >> 7;
      const int m = ((j & 63) * t) % 63;
      const float ang = (float)(6.283185307179586 * (double)m / 63.0);
      S[(size_t)j * NTT + t] = (j < 64) ? cosf(ang) : sinf(ang);
    }
  } else {
    #pragma unroll
    for (int q = 0; q < 4; ++q) {                // expand0: 2048*128 quads
      const int qid = (blk - 292) * 1024 + q * 256 + tid;
      const int b = qid >> 7, i0 = (qid & 127) * 4;
      const float4 v = *(const float4*)(x + (size_t)qid * 4);
      float xv[4] = {v.x, v.y, v.z, v.w};
      expand_quad(xv, Act + (size_t)b * KD, i0);
    }
  }
}

// ---------- expand: sum NSUM split-K partials -> Act bf16 (vectorized) ----------
template<int NSUM>
__global__ __launch_bounds__(256)
void expand_kernel(const float* __restrict__ src, u16* __restrict__ Act) {
  const int qid = blockIdx.x * 256 + threadIdx.x;  // quad id < 2048*128
  const int b = qid >> 7, i0 = (qid & 127) * 4;
  float xv[4] = {0.f, 0.f, 0.f, 0.f};
  #pragma unroll
  for (int t = 0; t < NSUM; ++t) {
    const float4 v = *(const float4*)(src + (size_t)t * NB * 512 + (size_t)qid * 4);
    xv[0] += v.x; xv[1] += v.y; xv[2] += v.z; xv[3] += v.w;
  }
  expand_quad(xv, Act + (size_t)b * KD, i0);
}

// ---------- GEMM: 128x128 tile, BK=64, 3-deep counted-vmcnt pipeline ----------
__device__ __forceinline__ void stage_tile(const u16* __restrict__ A, const u16* __restrict__ Bt,
                                           u16* As, u16* Bs, int rowBase, int colBase,
                                           int kOff, int wave, int lane) {
  const int sRow   = lane >> 3;
  const int sChunk = (lane & 7) ^ sRow;          // pre-swizzled global 16B chunk
  #pragma unroll
  for (int j = 0; j < 4; ++j) {
    const int slot = (wave * 4 + j) * 8;
    load_lds16(A  + (size_t)(rowBase + slot + sRow) * KD + kOff + sChunk * 8, As + slot * 64);
    load_lds16(Bt + (size_t)(colBase + slot + sRow) * KD + kOff + sChunk * 8, Bs + slot * 64);
  }
}

__device__ __forceinline__ void mma_step(const u16* As, const u16* Bs, f32x4 acc[4][4],
                                         int wr, int wc, int lane) {
  const int lr = lane & 15, lk8 = lane >> 4;
  #pragma unroll
  for (int ks = 0; ks < 2; ++ks) {
    short8 af[4], bf[4];
    const int kc = ks * 4 + lk8;
    #pragma unroll
    for (int m = 0; m < 4; ++m) {
      const int r = wr * 64 + m * 16 + lr;
      af[m] = *(const short8*)(As + r * 64 + ((kc ^ (r & 7)) * 8));
    }
    #pragma unroll
    for (int n = 0; n < 4; ++n) {
      const int r = wc * 64 + n * 16 + lr;
      bf[n] = *(const short8*)(Bs + r * 64 + ((kc ^ (r & 7)) * 8));
    }
    #pragma unroll
    for (int m = 0; m < 4; ++m)
      #pragma unroll
      for (int n = 0; n < 4; ++n)
        acc[m][n] = __builtin_amdgcn_mfma_f32_16x16x32_bf16(af[m], bf[n], acc[m][n], 0, 0, 0);
  }
}

template<int N, int KITER>
__device__ __forceinline__ void gemm_body(const u16* __restrict__ A, const u16* __restrict__ Bt,
                                          float* __restrict__ Cp, int bx, int by, int bz,
                                          u16* sm) {
  const int tid  = threadIdx.x;
  const int wave = tid >> 6, lane = tid & 63;
  const int rowBase = bx * 128, colBase = by * 128;
  const int kb0 = bz * KITER;
  const int wr = wave >> 1, wc = wave & 1;

  u16 *Ac = sm,             *Bc = sm + 8192;
  u16 *An = sm + 2 * 8192,  *Bn = sm + 3 * 8192;
  u16 *Af = sm + 4 * 8192,  *Bf = sm + 5 * 8192;

  f32x4 acc[4][4] = {};

  // prologue: tiles 0,1 in flight (8 loads each per wave)
  stage_tile(A, Bt, Ac, Bc, rowBase, colBase, (kb0 + 0) * 64, wave, lane);
  stage_tile(A, Bt, An, Bn, rowBase, colBase, (kb0 + 1) * 64, wave, lane);

  for (int t = 0; t < KITER - 1; ++t) {
    asm volatile("s_waitcnt vmcnt(8)" ::: "memory");   // tile t retired; t+1 in flight
    __builtin_amdgcn_s_barrier();
    if (t + 2 < KITER)
      stage_tile(A, Bt, Af, Bf, rowBase, colBase, (kb0 + t + 2) * 64, wave, lane);
    mma_step(Ac, Bc, acc, wr, wc, lane);
    __builtin_amdgcn_s_barrier();                       // protect Af from early overwrite
    u16* tp;
    tp = Ac; Ac = An; An = Af; Af = tp;
    tp = Bc; Bc = Bn; Bn = Bf; Bf = tp;
  }
  asm volatile("s_waitcnt vmcnt(0)" ::: "memory");      // final tile
  __builtin_amdgcn_s_barrier();
  mma_step(Ac, Bc, acc, wr, wc, lane);

  float* out = Cp + (size_t)bz * (size_t)NB * N;
  #pragma unroll
  for (int m = 0; m < 4; ++m) {
    const int row0 = rowBase + wr * 64 + m * 16 + (lane >> 4) * 4;   // row=(l>>4)*4+reg
    #pragma unroll
    for (int n = 0; n < 4; ++n) {
      const int col = colBase + wc * 64 + n * 16 + (lane & 15);      // col=l&15
      #pragma unroll
      for (int r = 0; r < 4; ++r)
        out[(size_t)(row0 + r) * N + col] = acc[m][n][r];
    }
  }
}

// fc GEMM: 1-D grid 256, XCD-locality swizzle (kept from r6).
__global__ __launch_bounds__(256, 1)
void gemm_fc(const u16* __restrict__ A, const u16* __restrict__ Bt, float* __restrict__ Cp) {
  __shared__ __align__(16) u16 sm[6 * 8192];     // 96 KiB triple buffer
  const int id  = blockIdx.x;
  const int xcd = id & 7;
  const int bz  = xcd >> 1;
  const int u   = id >> 3;
  const int bx  = ((u & 7) << 1) | (xcd & 1);
  const int by  = u >> 3;
  gemm_body<512, 18>(A, Bt, Cp, bx, by, bz, sm);
}

// theta GEMM: grid (16,1,8), kIter=9
__global__ __launch_bounds__(256, 1)
void gemm_th(const u16* __restrict__ A, const u16* __restrict__ Bt, float* __restrict__ Cp) {
  __shared__ __align__(16) u16 sm[6 * 8192];
  gemm_body<NTH, 9>(A, Bt, Cp, blockIdx.x, 0, blockIdx.z, sm);
}

// ---------- proj (+8-partial theta reduce): out = theta(2048x128) @ S(128x640) ----------
__global__ __launch_bounds__(256)
void proj_kernel(const float* __restrict__ Part, const float* __restrict__ S,
                 float* __restrict__ out) {
  __shared__ float Ts[64][129];
  const int tid = threadIdx.x;
  const int brow = blockIdx.x * 64, bcol = blockIdx.y * 64;
  for (int idx = tid; idx < 64 * 128; idx += 256) {
    const int r = idx >> 7, c = idx & 127;
    float s = 0.f;
    #pragma unroll
    for (int t = 0; t < 8; ++t)
      s += Part[(size_t)t * NB * NTH + (size_t)(brow + r) * NTH + c];
    Ts[r][c] = s;
  }
  __syncthreads();
  const int tx = tid & 15, ty = tid >> 4;
  const int r0 = ty * 4, c0 = tx * 4;
  float acc[4][4] = {};
  for (int k = 0; k < 128; ++k) {
    const float4 sv = *(const float4*)(S + (size_t)k * NTT + bcol + c0);
    #pragma unroll
    for (int rr = 0; rr < 4; ++rr) {
      const float tv = Ts[r0 + rr][k];
      acc[rr][0] += tv * sv.x; acc[rr][1] += tv * sv.y;
      acc[rr][2] += tv * sv.z; acc[rr][3] += tv * sv.w;
    }
  }
  #pragma unroll
  for (int rr = 0; rr < 4; ++rr) {
    const int b = brow + r0 + rr;
    #pragma unroll
    for (int cc = 0; cc < 4; ++cc) {
      const int t = bcol + c0 + cc;
      if (t < 512) out[(size_t)b * 512 + t] = acc[rr][cc];                            // backcast
      else         out[(size_t)NB * 512 + (size_t)b * NTH + (t - 512)] = acc[rr][cc]; // forecast
    }
  }
}

extern "C" void kernel_launch(void* const* d_in, const int* in_sizes, int n_in,
                              void* d_out, int out_size, void* d_ws, size_t ws_size,
                              hipStream_t stream) {
  (void)in_sizes; (void)n_in; (void)out_size; (void)ws_size;
  const float* x       = (const float*)d_in[0];
  const float* coef_fc = (const float*)d_in[1];
  const float* sb_fc   = (const float*)d_in[2];
  const float* ssp_fc  = (const float*)d_in[3];
  const float* coef_th = (const float*)d_in[4];
  const float* sb_th   = (const float*)d_in[5];
  const float* ssp_th  = (const float*)d_in[6];
  float* out = (float*)d_out;

  // ws layout: WtFc 18.9M | WtTh 1.18M | Act 18.9M | Part 16.8M | S 0.33M
  u16*  WtFc = (u16*)d_ws;
  u16*  WtTh = WtFc + (size_t)4 * 512 * KD;
  u16*  Act  = WtTh + (size_t)NTH * KD;
  float* Part = (float*)(Act + (size_t)NB * KD);
  float* S    = Part + (size_t)4 * NB * 512;

  setup_kernel<<<dim3(548), dim3(256), 0, stream>>>(coef_fc, sb_fc, ssp_fc,
                                                    coef_th, sb_th, ssp_th, x,
                                                    WtFc, WtTh, S, Act);
  for (int l = 0; l < 4; ++l) {
    gemm_fc<<<dim3(256), dim3(256), 0, stream>>>(Act, WtFc + (size_t)l * 512 * KD, Part);
    expand_kernel<4><<<dim3(1024), dim3(256), 0, stream>>>(Part, Act);
  }
  gemm_th<<<dim3(16, 1, 8), dim3(256), 0, stream>>>(Act, WtTh, Part);
  proj_kernel<<<dim3(32, 10), dim3(256), 0, stream>>>(Part, S, out);
}